// Round 3
// baseline (114.438 us; speedup 1.0000x reference)
//
#include <hip/hip_runtime.h>

#define NUM_CLASSES 6625
#define FEAT_DIM 96
#define NROWS 4096
#define CLAMP_MIN 1e-12
#define CLAMP_MAX 1e12
#define NSLOTS 64

// ws layout: [0..511]  double slots[64]
//            [512]     unsigned counter
__global__ __launch_bounds__(128) void init_kernel(double* slots, unsigned* counter) {
    const int t = threadIdx.x;
    if (t < NSLOTS) slots[t] = 0.0;
    if (t == NSLOTS) *counter = 0u;
}

// One WAVE per row (4 rows per 256-thread block). No LDS, no barriers.
// 8 independent argmax chains per lane -> 8 float4 loads in flight.
// Fused: f64 distance to centers[label], clamp, atomic accumulate into 64
// spread slots; last wave (atomic counter) folds slots -> final loss.
__global__ __launch_bounds__(256) void fused_kernel(
    const float* __restrict__ pred,
    const float* __restrict__ feats,
    const float* __restrict__ centers,
    double* slots, unsigned* counter,
    float* __restrict__ out)
{
    const int lane = threadIdx.x & 63;
    const int row  = blockIdx.x * 4 + (threadIdx.x >> 6);
    const float* p = pred + (size_t)row * NUM_CLASSES;

    // Row base element offset is row*6625 ≡ row (mod 4): scalar prefix to
    // reach 16B alignment for float4 loads.
    const int prefix = (4 - (row & 3)) & 3;
    const int nvec = (NUM_CLASSES - prefix) >> 2;   // 1655 or 1656
    const float4* pv = (const float4*)(p + prefix);

    // 8 chains; within each chain element indices increase monotonically, so
    // strict '>' keeps the first occurrence (ties across chains/lanes are
    // resolved by min-index at merge time) -> exact jnp.argmax semantics.
    float b0, b1, b2, b3, b4, b5, b6, b7;
    int   j0, j1, j2, j3, j4, j5, j6, j7;
    b0=b1=b2=b3=b4=b5=b6=b7 = -__builtin_inff();
    j0=j1=j2=j3=j4=j5=j6=j7 = NUM_CLASSES;

    if (lane < prefix) {                 // element indices 0..2 (smallest)
        float v = p[lane];
        if (v > b0) { b0 = v; j0 = lane; }
    }

    // 3 superiterations x 8 chains = 1536 float4 (chain c, iter k loads
    // vec index lane + 512k + 64c; wave load is 64 consecutive float4).
    #pragma unroll
    for (int k = 0; k < 3; ++k) {
        const int base = lane + 512 * k;
        float4 v0 = pv[base];
        float4 v1 = pv[base +  64];
        float4 v2 = pv[base + 128];
        float4 v3 = pv[base + 192];
        float4 v4 = pv[base + 256];
        float4 v5 = pv[base + 320];
        float4 v6 = pv[base + 384];
        float4 v7 = pv[base + 448];
        const int e = prefix + 4 * base;
        #define CHAIN(vv, bb, jj, off) \
            if (vv.x > bb) { bb = vv.x; jj = e + (off); } \
            if (vv.y > bb) { bb = vv.y; jj = e + (off) + 1; } \
            if (vv.z > bb) { bb = vv.z; jj = e + (off) + 2; } \
            if (vv.w > bb) { bb = vv.w; jj = e + (off) + 3; }
        CHAIN(v0, b0, j0,    0)
        CHAIN(v1, b1, j1,  256)
        CHAIN(v2, b2, j2,  512)
        CHAIN(v3, b3, j3,  768)
        CHAIN(v4, b4, j4, 1024)
        CHAIN(v5, b5, j5, 1280)
        CHAIN(v6, b6, j6, 1536)
        CHAIN(v7, b7, j7, 1792)
        #undef CHAIN
    }

    // Vector remainder: vec indices [1536, nvec) -> chains 0 and 1 (indices
    // stay monotonic within each chain).
    {
        const int i0 = 1536 + lane;
        if (i0 < nvec) {
            float4 v = pv[i0];
            const int e = prefix + 4 * i0;
            if (v.x > b0) { b0 = v.x; j0 = e; }
            if (v.y > b0) { b0 = v.y; j0 = e + 1; }
            if (v.z > b0) { b0 = v.z; j0 = e + 2; }
            if (v.w > b0) { b0 = v.w; j0 = e + 3; }
        }
        const int i1 = 1600 + lane;
        if (i1 < nvec) {
            float4 v = pv[i1];
            const int e = prefix + 4 * i1;
            if (v.x > b1) { b1 = v.x; j1 = e; }
            if (v.y > b1) { b1 = v.y; j1 = e + 1; }
            if (v.z > b1) { b1 = v.z; j1 = e + 2; }
            if (v.w > b1) { b1 = v.w; j1 = e + 3; }
        }
    }

    // Scalar tail (0..3 elements, the largest indices) -> chain 0; its prior
    // max index is <= prefix+4*(63+1536)+3 = 6402 < 6622, so still monotonic.
    {
        const int tailstart = prefix + 4 * nvec;
        const int tails = NUM_CLASSES - tailstart;
        if (lane < tails) {
            const int e = tailstart + lane;
            float v = p[e];
            if (v > b0) { b0 = v; j0 = e; }
        }
    }

    // Merge chains (value desc, index asc on tie).
    float best = b0; int bidx = j0;
    #define MERGE(bb, jj) if (bb > best || (bb == best && jj < bidx)) { best = bb; bidx = jj; }
    MERGE(b1, j1) MERGE(b2, j2) MERGE(b3, j3)
    MERGE(b4, j4) MERGE(b5, j5) MERGE(b6, j6) MERGE(b7, j7)
    #undef MERGE

    // Wave shuffle reduce (64 lanes).
    for (int off = 32; off > 0; off >>= 1) {
        float ov = __shfl_down(best, off, 64);
        int   oi = __shfl_down(bidx, off, 64);
        if (ov > best || (ov == best && oi < bidx)) { best = ov; bidx = oi; }
    }
    const int label = __shfl(bidx, 0, 64);

    // f64 squared distance: lane handles element `lane` (+ `lane+64` if lane<32).
    const float* frow = feats + row * FEAT_DIM;
    const float* crow = centers + (size_t)label * FEAT_DIM;
    double d0 = (double)frow[lane] - (double)crow[lane];
    double acc = d0 * d0;
    if (lane < 32) {
        double d1 = (double)frow[lane + 64] - (double)crow[lane + 64];
        acc += d1 * d1;
    }
    for (int off = 32; off > 0; off >>= 1)
        acc += __shfl_down(acc, off, 64);

    unsigned old = 0xFFFFFFFFu;
    if (lane == 0) {
        double dn = acc;
        dn = dn < CLAMP_MIN ? CLAMP_MIN : (dn > CLAMP_MAX ? CLAMP_MAX : dn);
        atomicAdd(&slots[row & (NSLOTS - 1)], dn);   // device-scope on CDNA
        __threadfence();
        old = atomicAdd(counter, 1u);
    }
    old = (unsigned)__shfl((int)old, 0, 64);

    // Last wave to arrive folds the 64 slots into the final loss.
    if (old == NROWS - 1) {
        __threadfence();
        double v = atomicAdd(&slots[lane], 0.0);     // coherent device-scope read
        for (int off = 32; off > 0; off >>= 1)
            v += __shfl_down(v, off, 64);
        if (lane == 0)
            out[0] = (float)(v / (double)NROWS
                             + (double)(NUM_CLASSES - 1) * CLAMP_MIN);
    }
}

extern "C" void kernel_launch(void* const* d_in, const int* in_sizes, int n_in,
                              void* d_out, int out_size, void* d_ws, size_t ws_size,
                              hipStream_t stream) {
    const float* feats   = (const float*)d_in[0];  // [4096, 96]
    const float* pred    = (const float*)d_in[1];  // [4096, 6625]
    const float* centers = (const float*)d_in[2];  // [6625, 96]
    double*   slots   = (double*)d_ws;                      // 64 * 8 B
    unsigned* counter = (unsigned*)((char*)d_ws + 512);
    float* out = (float*)d_out;

    init_kernel<<<1, 128, 0, stream>>>(slots, counter);
    fused_kernel<<<NROWS / 4, 256, 0, stream>>>(pred, feats, centers,
                                                slots, counter, out);
}

// Round 4
// 25.401 us; speedup vs baseline: 4.5052x; 4.5052x over previous
//
#include <hip/hip_runtime.h>

#define NUM_CLASSES 6625
#define FEAT_DIM 96
#define NROWS 4096
#define CLAMP_MIN 1e-12
#define CLAMP_MAX 1e12

// One 256-thread block per row. Each thread issues all 7 of its float4 loads
// up front (maximum MLP), compares into 7 independent chains (within-chain
// element indices are monotonically increasing, so strict '>' keeps the first
// occurrence == jnp.argmax semantics), then wave shuffle reduce + one LDS
// merge. Wave 0 computes the fused f64 squared distance to centers[label].
__global__ __launch_bounds__(256) void argmax_dist_kernel(
    const float* __restrict__ pred,
    const float* __restrict__ feats,
    const float* __restrict__ centers,
    double* __restrict__ dists)
{
    const int C = NUM_CLASSES;
    const int row = blockIdx.x;
    const int tid = threadIdx.x;
    const float* p = pred + (size_t)row * C;

    // Row base element offset is row*6625 ≡ row (mod 4): scalar prefix to
    // reach 16B alignment for float4 loads.
    const int prefix = (4 - (row & 3)) & 3;
    const int nvec = (C - prefix) >> 2;              // 1655 or 1656
    const float4* pv = (const float4*)(p + prefix);

    // ---- Issue every load this thread needs, back to back. ----
    // k = 0..5 always in range: max idx = 255 + 1280 = 1535 < 1655.
    float4 v0 = pv[tid];
    float4 v1 = pv[tid + 256];
    float4 v2 = pv[tid + 512];
    float4 v3 = pv[tid + 768];
    float4 v4 = pv[tid + 1024];
    float4 v5 = pv[tid + 1280];
    const int i6 = tid + 1536;
    const bool val6 = i6 < nvec;
    float4 v6 = pv[val6 ? i6 : (nvec - 1)];          // clamped, unconditional
    // Prefix scalar (element indices 0..prefix-1, the smallest).
    const bool valp = tid < prefix;
    float vp = p[valp ? tid : 0];
    // Tail scalars (largest element indices: tailstart..C-1).
    const int tailstart = prefix + 4 * nvec;
    const bool valt = tid < (C - tailstart);
    float vt = p[valt ? (tailstart + tid) : 0];

    // ---- Compare phase. ----
    float b0, b1, b2, b3, b4, b5, b6;
    int   j0, j1, j2, j3, j4, j5, j6;
    b0=b1=b2=b3=b4=b5=b6 = -__builtin_inff();
    j0=j1=j2=j3=j4=j5=j6 = C;

    // Chain 0 starts with the prefix element (index tid < prefix+4*tid).
    if (valp) { b0 = vp; j0 = tid; }

    #define CHAIN(vv, bb, jj, vecidx) { \
        const int e = prefix + 4 * (vecidx); \
        if (vv.x > bb) { bb = vv.x; jj = e; } \
        if (vv.y > bb) { bb = vv.y; jj = e + 1; } \
        if (vv.z > bb) { bb = vv.z; jj = e + 2; } \
        if (vv.w > bb) { bb = vv.w; jj = e + 3; } }
    CHAIN(v0, b0, j0, tid)
    CHAIN(v1, b1, j1, tid + 256)
    CHAIN(v2, b2, j2, tid + 512)
    CHAIN(v3, b3, j3, tid + 768)
    CHAIN(v4, b4, j4, tid + 1024)
    CHAIN(v5, b5, j5, tid + 1280)
    if (val6) CHAIN(v6, b6, j6, i6)
    #undef CHAIN
    // Tail folds into chain 6: its element indices exceed everything there.
    if (valt) {
        const int e = tailstart + tid;
        if (vt > b6) { b6 = vt; j6 = e; }
    }

    // Merge chains (value desc, index asc on tie).
    float best = b0; int bidx = j0;
    #define MERGE(bb, jj) if (bb > best || (bb == best && jj < bidx)) { best = bb; bidx = jj; }
    MERGE(b1, j1) MERGE(b2, j2) MERGE(b3, j3)
    MERGE(b4, j4) MERGE(b5, j5) MERGE(b6, j6)
    #undef MERGE

    // Wave shuffle reduce (64 lanes), no barrier.
    for (int off = 32; off > 0; off >>= 1) {
        float ov = __shfl_down(best, off, 64);
        int   oi = __shfl_down(bidx, off, 64);
        if (ov > best || (ov == best && oi < bidx)) { best = ov; bidx = oi; }
    }

    // Cross-wave merge: 4 partials through LDS, single barrier.
    __shared__ float swv[4];
    __shared__ int   swi[4];
    const int wave = tid >> 6;
    const int lane = tid & 63;
    if (lane == 0) { swv[wave] = best; swi[wave] = bidx; }
    __syncthreads();
    if (tid >= 64) return;

    float bv = swv[0]; int bi = swi[0];
    #pragma unroll
    for (int w = 1; w < 4; ++w) {
        float v2 = swv[w]; int i2 = swi[w];
        if (v2 > bv || (v2 == bv && i2 < bi)) { bv = v2; bi = i2; }
    }
    const int label = bi;  // uniform across wave 0

    // f64 squared distance: lane handles element lane (+ lane+64 if lane<32).
    const float* frow = feats + row * FEAT_DIM;
    const float* crow = centers + (size_t)label * FEAT_DIM;
    double d0 = (double)frow[lane] - (double)crow[lane];
    double acc = d0 * d0;
    if (lane < 32) {
        double d1 = (double)frow[lane + 64] - (double)crow[lane + 64];
        acc += d1 * d1;
    }
    for (int off = 32; off > 0; off >>= 1)
        acc += __shfl_down(acc, off, 64);
    if (lane == 0) {
        double dn = acc;
        dn = dn < CLAMP_MIN ? CLAMP_MIN : (dn > CLAMP_MAX ? CLAMP_MAX : dn);
        dists[row] = dn;
    }
}

// Single-block final reduction: mean over rows + the (C-1)*1e-12 constant from
// the reference's clip-after-mask on the zeroed columns.
__global__ __launch_bounds__(256) void reduce_kernel(
    const double* __restrict__ dists, float* __restrict__ out)
{
    const int tid = threadIdx.x;
    double s = 0.0;
    #pragma unroll
    for (int i = 0; i < NROWS / 256; ++i) s += dists[tid + i * 256];
    for (int off = 32; off > 0; off >>= 1)
        s += __shfl_down(s, off, 64);
    __shared__ double sw[4];
    const int wave = tid >> 6;
    const int lane = tid & 63;
    if (lane == 0) sw[wave] = s;
    __syncthreads();
    if (tid == 0) {
        double t = sw[0] + sw[1] + sw[2] + sw[3];
        out[0] = (float)(t / (double)NROWS
                         + (double)(NUM_CLASSES - 1) * CLAMP_MIN);
    }
}

extern "C" void kernel_launch(void* const* d_in, const int* in_sizes, int n_in,
                              void* d_out, int out_size, void* d_ws, size_t ws_size,
                              hipStream_t stream) {
    const float* feats   = (const float*)d_in[0];  // [4096, 96]
    const float* pred    = (const float*)d_in[1];  // [4096, 6625]
    const float* centers = (const float*)d_in[2];  // [6625, 96]
    double* dists = (double*)d_ws;                 // 4096 * 8 B = 32 KiB
    float* out = (float*)d_out;

    argmax_dist_kernel<<<NROWS, 256, 0, stream>>>(pred, feats, centers, dists);
    reduce_kernel<<<1, 256, 0, stream>>>(dists, out);
}